// Round 8
// baseline (602.012 us; speedup 1.0000x reference)
//
#include <hip/hip_runtime.h>
#include <math.h>

#define N_NODES 50000
#define N_EDGES 800000
#define D 128
#define E_DIM 16
#define DEPTH 3

typedef _Float16 half2_t __attribute__((ext_vector_type(2)));
typedef _Float16 half4_t __attribute__((ext_vector_type(4)));
typedef _Float16 half8_t __attribute__((ext_vector_type(8)));
typedef float floatx4 __attribute__((ext_vector_type(4)));

#if defined(__has_builtin)
#if __has_builtin(__builtin_amdgcn_fdot2)
#define FDOT2(a, b, c) __builtin_amdgcn_fdot2((a), (b), (c), false)
#endif
#endif
#ifndef FDOT2
static __device__ __forceinline__ float fdot2_sw(half2_t a, half2_t b, float c) {
    return fmaf((float)a.x, (float)b.x, fmaf((float)a.y, (float)b.y, c));
}
#define FDOT2(a, b, c) fdot2_sw((a), (b), (c))
#endif

// ---------------- CSR scan: one kernel, decoupled lookback ----------------
// 49 blocks (all co-resident on 256 CUs -> spin is deadlock-free). Block b
// publishes its total via atomics, then 48 threads spin-fetch predecessors
// in parallel and a block-reduce forms the prefix. Replaces scan1+scanadd.

#define SCAN_BLOCKS 49   // ceil(N_NODES/1024)

__global__ __launch_bounds__(256) void k_scan(
    const int* __restrict__ deg, int* __restrict__ off, int* __restrict__ head,
    int* __restrict__ bsum, int* __restrict__ bflag) {
    __shared__ int s[256];
    int t = threadIdx.x;
    int base = blockIdx.x * 1024;
    int v[4]; int runv[4];
    int sum = 0;
#pragma unroll
    for (int j = 0; j < 4; j++) {
        int idx = base + t * 4 + j;
        int x = (idx < N_NODES) ? deg[idx] : 0;
        v[j] = x; sum += x;
    }
    s[t] = sum;
    __syncthreads();
    for (int d2 = 1; d2 < 256; d2 <<= 1) {
        int val = (t >= d2) ? s[t - d2] : 0;
        __syncthreads();
        s[t] += val;
        __syncthreads();
    }
    int run = (t > 0) ? s[t - 1] : 0;
#pragma unroll
    for (int j = 0; j < 4; j++) { run += v[j]; runv[j] = run; }
    if (t == 0) {
        atomicExch(&bsum[blockIdx.x], s[255]);
        __threadfence();
        atomicExch(&bflag[blockIdx.x], 1);
    }
    int p = 0;
    if (t < blockIdx.x) {
        while (atomicAdd(&bflag[t], 0) == 0) {}
        p = atomicAdd(&bsum[t], 0);
    }
    __syncthreads();            // s[] reuse
    s[t] = p;
    __syncthreads();
    for (int d2 = 128; d2 > 0; d2 >>= 1) {
        if (t < d2) s[t] += s[t + d2];
        __syncthreads();
    }
    int prefix = s[0];
    if (blockIdx.x == 0 && t == 0) off[0] = 0;
#pragma unroll
    for (int j = 0; j < 4; j++) {
        int idx = base + t * 4 + j;
        if (idx < N_NODES) {
            int incl = runv[j] + prefix;
            off[idx + 1] = incl;
            head[idx] = incl - v[j];   // exclusive prefix = scatter start
        }
    }
}

// Scatter edges into dst-sorted order. sorted[pos] = src-row BYTE offset.
// e-attr rows permuted along (f32->f16 convert fused): k_layer reads e-attrs
// sequentially in te (round-6: removes one random-gather stream).
__global__ void k_scatter(const int* __restrict__ src, const int* __restrict__ dst,
                          int* __restrict__ head, int* __restrict__ sorted,
                          const float* __restrict__ ea, _Float16* __restrict__ ea_s) {
    int e = blockIdx.x * blockDim.x + threadIdx.x;
    if (e < N_EDGES) {
        int d = dst[e];
        int pos = atomicAdd(&head[d], 1);
        sorted[pos] = src[e] << 8;
        const float* ep = ea + (size_t)e * E_DIM;
        float4 a = *(const float4*)(ep);
        float4 b = *(const float4*)(ep + 4);
        float4 c = *(const float4*)(ep + 8);
        float4 f = *(const float4*)(ep + 12);
        half8_t lo = {(_Float16)a.x, (_Float16)a.y, (_Float16)a.z, (_Float16)a.w,
                      (_Float16)b.x, (_Float16)b.y, (_Float16)b.z, (_Float16)b.w};
        half8_t hi = {(_Float16)c.x, (_Float16)c.y, (_Float16)c.z, (_Float16)c.w,
                      (_Float16)f.x, (_Float16)f.y, (_Float16)f.z, (_Float16)f.w};
        _Float16* op = ea_s + (size_t)pos * E_DIM;
        *(half8_t*)op = lo;
        *(half8_t*)(op + 8) = hi;
    }
}

// ------- prep: x f16 convert + MFMA weight packing + We packing + dst hist ---

#define NB_X   3125    // N_NODES*D/8/256
#define NB_W   384     // 6*16384/256
#define NB_WE  12      // 3*1024 half2 / 256
#define NB_H   3125    // N_EDGES/256
#define NB_PRE (NB_X + NB_W + NB_WE)

__global__ void k_prep(const float* __restrict__ x,
                       const float* __restrict__ W1, const float* __restrict__ W2,
                       const float* __restrict__ WeAll, const int* __restrict__ dst,
                       _Float16* __restrict__ xh,
                       _Float16* __restrict__ Wp, _Float16* __restrict__ Weh,
                       int* __restrict__ deg) {
    int b = blockIdx.x;
    if (b < NB_X) {
        int i = b * 256 + threadIdx.x;
        int base = i * 8;
        float4 a = *(const float4*)(x + base);
        float4 c = *(const float4*)(x + base + 4);
        half8_t h = {(_Float16)a.x, (_Float16)a.y, (_Float16)a.z, (_Float16)a.w,
                     (_Float16)c.x, (_Float16)c.y, (_Float16)c.z, (_Float16)c.w};
        *(half8_t*)(xh + base) = h;
    } else if (b < NB_X + NB_W) {
        int t = (b - NB_X) * 256 + threadIdx.x;
        int j    = t & 7;
        int lane = (t >> 3) & 63;
        int nb   = (t >> 9) & 7;
        int kb   = (t >> 12) & 3;
        int mat  = t >> 14;
        int layer = mat >> 1, which = mat & 1;
        const float* Wsrc = (which ? W2 : W1) + (size_t)layer * D * D;
        int k = kb * 32 + (lane >> 4) * 8 + j;
        int n = nb * 16 + (lane & 15);
        Wp[t] = (_Float16)Wsrc[k * D + n];
    } else if (b < NB_PRE) {
        // pack We as half2 pairs in k: layout [layer][c=0..31][kp=0..7][f=0..3]
        int t = (b - NB_X - NB_W) * 256 + threadIdx.x;  // 0..3071 (half2 index)
        int layer = t >> 10;
        int idx = t & 1023;
        int c = idx >> 5, kp = (idx >> 2) & 7, f = idx & 3;
        const float* Wsrc = WeAll + (size_t)layer * E_DIM * D;
        half2_t v = {(_Float16)Wsrc[(2 * kp) * D + 4 * c + f],
                     (_Float16)Wsrc[(2 * kp + 1) * D + 4 * c + f]};
        *(half2_t*)(Weh + 2 * (size_t)t) = v;
    } else {
        int e = (b - NB_PRE) * 256 + threadIdx.x;
        if (e < N_EDGES) atomicAdd(&deg[dst[e]], 1);
    }
}

// ---------------- fused per-layer: aggregation + node MLP ----------------
// Block = 256 thr / 4 waves / 32 nodes (grid 1563 ~= r3's agg granularity:
// 8 nodes/wave, 2-group unroll-2 -> same chains/CU as the proven 79us k_agg).
// Agg writes h into LDS (no h0 HBM roundtrip, no mlp staging pass). MLP is
// split-column: wave pair (2t,2t+1) owns 16-row MFMA tile, each wave 64 cols.
// Single 32x136 f16 LDS buffer reused H->G: A-fragments are prefetched into
// registers, barriers make the alias safe. 3 barriers total.

#define NL_BLOCKS ((N_NODES + 31) / 32)   // 1563

template <bool LAST>
__global__ __launch_bounds__(256, 6) void k_layer(
    const _Float16* __restrict__ xb, const _Float16* __restrict__ ea_s,
    const int* __restrict__ sorted, const int* __restrict__ off,
    const _Float16* __restrict__ Wea_l, const float* __restrict__ be_l,
    const float* __restrict__ eps_ptr,
    const _Float16* __restrict__ W1p, const float* __restrict__ b1,
    const _Float16* __restrict__ W2p, const float* __restrict__ b2,
    float* __restrict__ outf, _Float16* __restrict__ outh) {
    __shared__ _Float16 sH[32 * 136];    // 8704 B, reused H -> G
    int n0 = blockIdx.x * 32;
    int w = threadIdx.x >> 6;
    int lane = threadIdx.x & 63;

    // ================= agg phase (r3/r6-proven inner loop) =================
    {
        int g = lane >> 5;        // group 0/1
        int c = lane & 31;        // feature slice: feats 4c..4c+3

        half2_t w2[8][4];
        {
            const _Float16* wp = Wea_l + c * 64;
#pragma unroll
            for (int kp = 0; kp < 8; kp++) {
                half8_t wv = *(const half8_t*)(wp + kp * 8);
                w2[kp][0] = half2_t{wv[0], wv[1]};
                w2[kp][1] = half2_t{wv[2], wv[3]};
                w2[kp][2] = half2_t{wv[4], wv[5]};
                w2[kp][3] = half2_t{wv[6], wv[7]};
            }
        }
        float bev[4];
        {
            float4 bb = *(const float4*)(be_l + 4 * c);
            bev[0] = bb.x; bev[1] = bb.y; bev[2] = bb.z; bev[3] = bb.w;
        }
        float epsv = 1.0f + eps_ptr[0];

        const char* easb = (const char*)ea_s;
        const char* xbb = (const char*)xb;
        int coff = c << 3;

        int nstart = n0 + 8 * w;
        if (nstart < N_NODES) {
            int nend = nstart + 8;
            if (nend > N_NODES) nend = N_NODES;

            int tcur = __builtin_amdgcn_readfirstlane(off[nstart]);
            for (int n = nstart; n < nend; ++n) {
                float acc[4] = {0.f, 0.f, 0.f, 0.f};
                int t0 = tcur;
                int t1 = __builtin_amdgcn_readfirstlane(off[n + 1]);
                tcur = t1;

                auto process = [&](int te) {
                    int sx = sorted[te];                       // src byte off
                    const char* ep = easb + ((size_t)te << 5); // sequential
                    half8_t elo = *(const half8_t*)ep;
                    half8_t ehi = *(const half8_t*)(ep + 16);
                    half4_t xv = *(const half4_t*)(xbb + sx + coff);
                    float p0 = bev[0], p1 = bev[1], p2 = bev[2], p3 = bev[3];
#pragma unroll
                    for (int kp = 0; kp < 4; kp++) {
                        half2_t e2 = half2_t{elo[2 * kp], elo[2 * kp + 1]};
                        p0 = FDOT2(e2, w2[kp][0], p0);
                        p1 = FDOT2(e2, w2[kp][1], p1);
                        p2 = FDOT2(e2, w2[kp][2], p2);
                        p3 = FDOT2(e2, w2[kp][3], p3);
                    }
#pragma unroll
                    for (int kp = 0; kp < 4; kp++) {
                        half2_t e2 = half2_t{ehi[2 * kp], ehi[2 * kp + 1]};
                        p0 = FDOT2(e2, w2[kp + 4][0], p0);
                        p1 = FDOT2(e2, w2[kp + 4][1], p1);
                        p2 = FDOT2(e2, w2[kp + 4][2], p2);
                        p3 = FDOT2(e2, w2[kp + 4][3], p3);
                    }
                    acc[0] += fmaxf((float)xv[0] + p0, 0.f);
                    acc[1] += fmaxf((float)xv[1] + p1, 0.f);
                    acc[2] += fmaxf((float)xv[2] + p2, 0.f);
                    acc[3] += fmaxf((float)xv[3] + p3, 0.f);
                };

                int t = t0;
                for (; t + 4 <= t1; t += 4) {
                    process(t + g);
                    process(t + g + 2);
                }
                for (; t < t1; t += 2) {
                    int te = t + g;
                    if (te < t1) process(te);
                }

#pragma unroll
                for (int f = 0; f < 4; f++) acc[f] += __shfl_xor(acc[f], 32, 64);

                if (g == 0) {
                    half4_t xv = *(const half4_t*)(xb + (size_t)n * D + 4 * c);
                    half4_t oh;
#pragma unroll
                    for (int f = 0; f < 4; f++)
                        oh[f] = (_Float16)(fmaf(epsv, (float)xv[f], acc[f]));
                    *(half4_t*)&sH[(n - n0) * 136 + 4 * c] = oh;
                }
            }
        }
    }
    __syncthreads();   // barrier 1: H complete in LDS

    // ================= mlp phase (split-column MFMA) =================
    int q = lane >> 4, r16 = lane & 15;
    int tile = w >> 1;              // row tile 0/1 (rows tile*16..+15)
    int nbb = (w & 1) * 4;          // column block base (4 of 8 nb's)
    int mrow = tile * 16 + r16;

    // prefetch A rows (H) into registers so the LDS buffer can be reused
    half8_t av[4];
#pragma unroll
    for (int kb = 0; kb < 4; kb++)
        av[kb] = *(const half8_t*)&sH[mrow * 136 + kb * 32 + q * 8];
    __syncthreads();   // barrier 2: all H reads done, buffer free for G

    floatx4 acc[4];
#pragma unroll
    for (int j = 0; j < 4; j++) acc[j] = floatx4{0.f, 0.f, 0.f, 0.f};
#pragma unroll
    for (int kb = 0; kb < 4; kb++) {
#pragma unroll
        for (int j = 0; j < 4; j++) {
            int nb = nbb + j;
            half8_t bv = *(const half8_t*)(W1p + (size_t)((kb * 8 + nb) * 64 + lane) * 8);
            acc[j] = __builtin_amdgcn_mfma_f32_16x16x32_f16(av[kb], bv, acc[j], 0, 0, 0);
        }
    }
#pragma unroll
    for (int j = 0; j < 4; j++) {
        int col = (nbb + j) * 16 + r16;
        float bb = b1[col];
#pragma unroll
        for (int r = 0; r < 4; r++) {
            float v = acc[j][r] + bb;
            float gl = 0.5f * v * (1.0f + erff(v * 0.70710678118654752f));
            sH[(tile * 16 + q * 4 + r) * 136 + col] = (_Float16)gl;
        }
    }
    __syncthreads();   // barrier 3: G complete

#pragma unroll
    for (int kb = 0; kb < 4; kb++)
        av[kb] = *(const half8_t*)&sH[mrow * 136 + kb * 32 + q * 8];
#pragma unroll
    for (int j = 0; j < 4; j++) acc[j] = floatx4{0.f, 0.f, 0.f, 0.f};
#pragma unroll
    for (int kb = 0; kb < 4; kb++) {
#pragma unroll
        for (int j = 0; j < 4; j++) {
            int nb = nbb + j;
            half8_t bv = *(const half8_t*)(W2p + (size_t)((kb * 8 + nb) * 64 + lane) * 8);
            acc[j] = __builtin_amdgcn_mfma_f32_16x16x32_f16(av[kb], bv, acc[j], 0, 0, 0);
        }
    }
#pragma unroll
    for (int j = 0; j < 4; j++) {
        int col = (nbb + j) * 16 + r16;
        float bb = b2[col];
#pragma unroll
        for (int r = 0; r < 4; r++) {
            int n = n0 + tile * 16 + q * 4 + r;
            if (n < N_NODES) {
                float v = acc[j][r] + bb;
                if (LAST) outf[(size_t)n * D + col] = v;
                else      outh[(size_t)n * D + col] = (_Float16)v;
            }
        }
    }
}

// ---------------- launch ----------------

static inline size_t align_up(size_t v, size_t a) { return (v + a - 1) & ~(a - 1); }

extern "C" void kernel_launch(void* const* d_in, const int* in_sizes, int n_in,
                              void* d_out, int out_size, void* d_ws, size_t ws_size,
                              hipStream_t stream) {
    const float* x         = (const float*)d_in[0];
    const float* edge_attr = (const float*)d_in[1];
    const float* W1        = (const float*)d_in[2];
    const float* b1        = (const float*)d_in[3];
    const float* W2        = (const float*)d_in[4];
    const float* b2        = (const float*)d_in[5];
    const float* We        = (const float*)d_in[6];
    const float* be        = (const float*)d_in[7];
    const float* eps       = (const float*)d_in[8];
    const int*   src       = (const int*)d_in[9];
    const int*   dst       = ((const int*)d_in[9]) + N_EDGES;

    char* w = (char*)d_ws;
    int*  off    = (int*)w;  w += align_up((N_NODES + 1) * sizeof(int), 16);
    int*  deg    = (int*)w;  w += N_NODES * sizeof(int);        // deg + bflag contiguous
    int*  bflag  = (int*)w;  w += 64 * sizeof(int);             // (memset'd together)
    int*  head   = (int*)w;  w += align_up(N_NODES * sizeof(int), 16);
    int*  bsum   = (int*)w;  w += 64 * sizeof(int);
    int*  sorted = (int*)w;  w += align_up((size_t)N_EDGES * sizeof(int), 16);
    _Float16* xb0 = (_Float16*)w; w += (size_t)N_NODES * D * 2;
    _Float16* xb1 = (_Float16*)w; w += (size_t)N_NODES * D * 2;
    _Float16* ea_s = (_Float16*)w; w += (size_t)N_EDGES * E_DIM * 2 + 1024;
    _Float16* Wp  = (_Float16*)w; w += (size_t)6 * 16384 * 2;
    _Float16* Weh = (_Float16*)w; w += (size_t)3 * 2048 * 2;

    // ---- CSR build + prep: 4 dispatches ----
    hipMemsetAsync(deg, 0, (N_NODES + 64) * sizeof(int), stream);   // deg + bflag
    k_prep<<<NB_PRE + NB_H, 256, 0, stream>>>(
        x, W1, W2, We, dst, xb0, Wp, Weh, deg);
    k_scan<<<SCAN_BLOCKS, 256, 0, stream>>>(deg, off, head, bsum, bflag);
    k_scatter<<<(N_EDGES + 255) / 256, 256, 0, stream>>>(
        src, dst, head, sorted, edge_attr, ea_s);

    // ---- 3 fused layers ----
    _Float16* xcur = xb0;
    _Float16* xnxt = xb1;
    for (int l = 0; l < DEPTH; l++) {
        const _Float16* W1p = Wp + (size_t)(l * 2 + 0) * 16384;
        const _Float16* W2p = Wp + (size_t)(l * 2 + 1) * 16384;
        if (l == DEPTH - 1) {
            k_layer<true><<<NL_BLOCKS, 256, 0, stream>>>(
                xcur, ea_s, sorted, off,
                Weh + (size_t)l * 2048, be + (size_t)l * D, eps + l,
                W1p, b1 + (size_t)l * D, W2p, b2 + (size_t)l * D,
                (float*)d_out, nullptr);
        } else {
            k_layer<false><<<NL_BLOCKS, 256, 0, stream>>>(
                xcur, ea_s, sorted, off,
                Weh + (size_t)l * 2048, be + (size_t)l * D, eps + l,
                W1p, b1 + (size_t)l * D, W2p, b2 + (size_t)l * D,
                nullptr, xnxt);
        }
        _Float16* tmp = xcur; xcur = xnxt; xnxt = tmp;
    }
}

// Round 9
// 597.466 us; speedup vs baseline: 1.0076x; 1.0076x over previous
//
#include <hip/hip_runtime.h>
#include <math.h>

#define N_NODES 50000
#define N_EDGES 800000
#define D 128
#define E_DIM 16
#define DEPTH 3

typedef _Float16 half2_t __attribute__((ext_vector_type(2)));
typedef _Float16 half4_t __attribute__((ext_vector_type(4)));
typedef _Float16 half8_t __attribute__((ext_vector_type(8)));
typedef float floatx4 __attribute__((ext_vector_type(4)));

#if defined(__has_builtin)
#if __has_builtin(__builtin_amdgcn_fdot2)
#define FDOT2(a, b, c) __builtin_amdgcn_fdot2((a), (b), (c), false)
#endif
#endif
#ifndef FDOT2
static __device__ __forceinline__ float fdot2_sw(half2_t a, half2_t b, float c) {
    return fmaf((float)a.x, (float)b.x, fmaf((float)a.y, (float)b.y, c));
}
#define FDOT2(a, b, c) fdot2_sw((a), (b), (c))
#endif

// ---------------- CSR scan: one kernel, decoupled lookback (r8-proven) -------
#define SCAN_BLOCKS 49   // ceil(N_NODES/1024)

__global__ __launch_bounds__(256) void k_scan(
    const int* __restrict__ deg, int* __restrict__ off, int* __restrict__ head,
    int* __restrict__ bsum, int* __restrict__ bflag) {
    __shared__ int s[256];
    int t = threadIdx.x;
    int base = blockIdx.x * 1024;
    int v[4]; int runv[4];
    int sum = 0;
#pragma unroll
    for (int j = 0; j < 4; j++) {
        int idx = base + t * 4 + j;
        int x = (idx < N_NODES) ? deg[idx] : 0;
        v[j] = x; sum += x;
    }
    s[t] = sum;
    __syncthreads();
    for (int d2 = 1; d2 < 256; d2 <<= 1) {
        int val = (t >= d2) ? s[t - d2] : 0;
        __syncthreads();
        s[t] += val;
        __syncthreads();
    }
    int run = (t > 0) ? s[t - 1] : 0;
#pragma unroll
    for (int j = 0; j < 4; j++) { run += v[j]; runv[j] = run; }
    if (t == 0) {
        atomicExch(&bsum[blockIdx.x], s[255]);
        __threadfence();
        atomicExch(&bflag[blockIdx.x], 1);
    }
    int p = 0;
    if (t < blockIdx.x) {
        while (atomicAdd(&bflag[t], 0) == 0) {}
        p = atomicAdd(&bsum[t], 0);
    }
    __syncthreads();            // s[] reuse
    s[t] = p;
    __syncthreads();
    for (int d2 = 128; d2 > 0; d2 >>= 1) {
        if (t < d2) s[t] += s[t + d2];
        __syncthreads();
    }
    int prefix = s[0];
    if (blockIdx.x == 0 && t == 0) off[0] = 0;
#pragma unroll
    for (int j = 0; j < 4; j++) {
        int idx = base + t * 4 + j;
        if (idx < N_NODES) {
            int incl = runv[j] + prefix;
            off[idx + 1] = incl;
            head[idx] = incl - v[j];   // exclusive prefix = scatter start
        }
    }
}

// Scatter edges into dst-sorted order. sorted[pos] = src-row BYTE offset.
// e-attr rows permuted along (f32->f16 convert fused): k_agg reads e-attrs
// sequentially in te (round-6: removes one random-gather stream).
__global__ void k_scatter(const int* __restrict__ src, const int* __restrict__ dst,
                          int* __restrict__ head, int* __restrict__ sorted,
                          const float* __restrict__ ea, _Float16* __restrict__ ea_s) {
    int e = blockIdx.x * blockDim.x + threadIdx.x;
    if (e < N_EDGES) {
        int d = dst[e];
        int pos = atomicAdd(&head[d], 1);
        sorted[pos] = src[e] << 8;
        const float* ep = ea + (size_t)e * E_DIM;
        float4 a = *(const float4*)(ep);
        float4 b = *(const float4*)(ep + 4);
        float4 c = *(const float4*)(ep + 8);
        float4 f = *(const float4*)(ep + 12);
        half8_t lo = {(_Float16)a.x, (_Float16)a.y, (_Float16)a.z, (_Float16)a.w,
                      (_Float16)b.x, (_Float16)b.y, (_Float16)b.z, (_Float16)b.w};
        half8_t hi = {(_Float16)c.x, (_Float16)c.y, (_Float16)c.z, (_Float16)c.w,
                      (_Float16)f.x, (_Float16)f.y, (_Float16)f.z, (_Float16)f.w};
        _Float16* op = ea_s + (size_t)pos * E_DIM;
        *(half8_t*)op = lo;
        *(half8_t*)(op + 8) = hi;
    }
}

// ------- prep: x f16 convert + MFMA weight packing + We packing + dst hist ---

#define NB_X   3125    // N_NODES*D/8/256
#define NB_W   384     // 6*16384/256
#define NB_WE  12      // 3*1024 half2 / 256
#define NB_H   3125    // N_EDGES/256
#define NB_PRE (NB_X + NB_W + NB_WE)

__global__ void k_prep(const float* __restrict__ x,
                       const float* __restrict__ W1, const float* __restrict__ W2,
                       const float* __restrict__ WeAll, const int* __restrict__ dst,
                       _Float16* __restrict__ xh,
                       _Float16* __restrict__ Wp, _Float16* __restrict__ Weh,
                       int* __restrict__ deg) {
    int b = blockIdx.x;
    if (b < NB_X) {
        int i = b * 256 + threadIdx.x;
        int base = i * 8;
        float4 a = *(const float4*)(x + base);
        float4 c = *(const float4*)(x + base + 4);
        half8_t h = {(_Float16)a.x, (_Float16)a.y, (_Float16)a.z, (_Float16)a.w,
                     (_Float16)c.x, (_Float16)c.y, (_Float16)c.z, (_Float16)c.w};
        *(half8_t*)(xh + base) = h;
    } else if (b < NB_X + NB_W) {
        int t = (b - NB_X) * 256 + threadIdx.x;
        int j    = t & 7;
        int lane = (t >> 3) & 63;
        int nb   = (t >> 9) & 7;
        int kb   = (t >> 12) & 3;
        int mat  = t >> 14;
        int layer = mat >> 1, which = mat & 1;
        const float* Wsrc = (which ? W2 : W1) + (size_t)layer * D * D;
        int k = kb * 32 + (lane >> 4) * 8 + j;
        int n = nb * 16 + (lane & 15);
        Wp[t] = (_Float16)Wsrc[k * D + n];
    } else if (b < NB_PRE) {
        // pack We as half2 pairs in k: layout [layer][c=0..31][kp=0..7][f=0..3]
        int t = (b - NB_X - NB_W) * 256 + threadIdx.x;  // 0..3071 (half2 index)
        int layer = t >> 10;
        int idx = t & 1023;
        int c = idx >> 5, kp = (idx >> 2) & 7, f = idx & 3;
        const float* Wsrc = WeAll + (size_t)layer * E_DIM * D;
        half2_t v = {(_Float16)Wsrc[(2 * kp) * D + 4 * c + f],
                     (_Float16)Wsrc[(2 * kp + 1) * D + 4 * c + f]};
        *(half2_t*)(Weh + 2 * (size_t)t) = v;
    } else {
        int e = (b - NB_PRE) * 256 + threadIdx.x;
        if (e < N_EDGES) atomicAdd(&deg[dst[e]], 1);
    }
}

// ---------------- per-layer: aggregation (r3/r6-proven structure) ----------
// Persistent waves, 6 blocks/CU (grid 1536), contiguous balanced node ranges,
// unroll-2 per 32-lane group (4 gather chains/wave — the compiler's sustained
// max, rounds 1/4/5). e-attrs pre-permuted (sequential in te) + NONTEMPORAL:
// each ea_s line is read exactly once — keep it out of L2 so the x rows
// (the ~100MB/dispatch refetch stream) keep their L2 residency.

#define AGG_BLOCKS 1536
#define AGG_WAVES  (AGG_BLOCKS * 4)   // 6144
#define AGG_Q      (N_NODES / AGG_WAVES)          // 8
#define AGG_R      (N_NODES - AGG_Q * AGG_WAVES)  // 848

__global__ __launch_bounds__(256, 6) void k_agg(
    const _Float16* __restrict__ xb, const _Float16* __restrict__ ea_s,
    const int* __restrict__ sorted, const int* __restrict__ off,
    const _Float16* __restrict__ Wea_l, const float* __restrict__ be_l,
    const float* __restrict__ eps_ptr, _Float16* __restrict__ h0) {
    int wid = blockIdx.x * 4 + (threadIdx.x >> 6);
    int lane = threadIdx.x & 63;
    int g = lane >> 5;        // group 0/1
    int c = lane & 31;        // feature slice: feats 4c..4c+3

    // pre-packed We pairs: 64 contiguous halfs per lane, vector loads, no cvt
    half2_t w2[8][4];
    {
        const _Float16* wp = Wea_l + c * 64;
#pragma unroll
        for (int kp = 0; kp < 8; kp++) {
            half8_t wv = *(const half8_t*)(wp + kp * 8);
            w2[kp][0] = half2_t{wv[0], wv[1]};
            w2[kp][1] = half2_t{wv[2], wv[3]};
            w2[kp][2] = half2_t{wv[4], wv[5]};
            w2[kp][3] = half2_t{wv[6], wv[7]};
        }
    }
    float bev[4];
    {
        float4 bb = *(const float4*)(be_l + 4 * c);
        bev[0] = bb.x; bev[1] = bb.y; bev[2] = bb.z; bev[3] = bb.w;
    }
    float epsv = 1.0f + eps_ptr[0];

    const char* easb = (const char*)ea_s;
    const char* xbb = (const char*)xb;
    int coff = c << 3;

    // balanced contiguous partition: wave wid -> [nstart, nstart+ncnt)
    int nstart = wid * AGG_Q + (wid < AGG_R ? wid : AGG_R);
    int ncnt   = AGG_Q + (wid < AGG_R ? 1 : 0);
    int nend   = nstart + ncnt;

    int tcur = __builtin_amdgcn_readfirstlane(off[nstart]);
    for (int n = nstart; n < nend; ++n) {
        float acc[4] = {0.f, 0.f, 0.f, 0.f};
        int t0 = tcur;
        int t1 = __builtin_amdgcn_readfirstlane(off[n + 1]);
        tcur = t1;

        auto process = [&](int te) {
            int sx = sorted[te];                       // src-row byte offset
            const char* ep = easb + ((size_t)te << 5); // sequential in te
            half8_t elo = __builtin_nontemporal_load((const half8_t*)ep);
            half8_t ehi = __builtin_nontemporal_load((const half8_t*)(ep + 16));
            half4_t xv = *(const half4_t*)(xbb + sx + coff);
            float p0 = bev[0], p1 = bev[1], p2 = bev[2], p3 = bev[3];
#pragma unroll
            for (int kp = 0; kp < 4; kp++) {
                half2_t e2 = half2_t{elo[2 * kp], elo[2 * kp + 1]};
                p0 = FDOT2(e2, w2[kp][0], p0);
                p1 = FDOT2(e2, w2[kp][1], p1);
                p2 = FDOT2(e2, w2[kp][2], p2);
                p3 = FDOT2(e2, w2[kp][3], p3);
            }
#pragma unroll
            for (int kp = 0; kp < 4; kp++) {
                half2_t e2 = half2_t{ehi[2 * kp], ehi[2 * kp + 1]};
                p0 = FDOT2(e2, w2[kp + 4][0], p0);
                p1 = FDOT2(e2, w2[kp + 4][1], p1);
                p2 = FDOT2(e2, w2[kp + 4][2], p2);
                p3 = FDOT2(e2, w2[kp + 4][3], p3);
            }
            acc[0] += fmaxf((float)xv[0] + p0, 0.f);
            acc[1] += fmaxf((float)xv[1] + p1, 0.f);
            acc[2] += fmaxf((float)xv[2] + p2, 0.f);
            acc[3] += fmaxf((float)xv[3] + p3, 0.f);
        };

        int t = t0;
        for (; t + 4 <= t1; t += 4) {      // both groups, 2 slots each
            process(t + g);
            process(t + g + 2);
        }
        for (; t < t1; t += 2) {           // remainder (<=3 edges)
            int te = t + g;
            if (te < t1) process(te);
        }

        // cross-group reduction: lane l += lane l^32
#pragma unroll
        for (int f = 0; f < 4; f++) acc[f] += __shfl_xor(acc[f], 32, 64);

        if (g == 0) {
            half4_t xv = *(const half4_t*)(xb + (size_t)n * D + 4 * c);
            half4_t oh;
#pragma unroll
            for (int f = 0; f < 4; f++)
                oh[f] = (_Float16)(fmaf(epsv, (float)xv[f], acc[f]));
            *(half4_t*)(h0 + (size_t)n * D + 4 * c) = oh;
        }
    }
}

// ---------------- per-layer: fused node MLP via MFMA f16 ----------------
// Single-buffer, zero-barrier version: GEMM1 A-fragments load directly from
// global h0 (L2/L3-hot, 4x16B per lane; rows clamped for OOB — garbage rows
// only corrupt D rows that are never stored). Only G needs LDS (17.4 KB,
// half the old footprint -> ~6 blocks/CU). Wave w writes exactly the sG rows
// it re-reads for GEMM2, so no __syncthreads at all.

template <bool LAST>
__global__ __launch_bounds__(256, 6) void k_mlp(
    const _Float16* __restrict__ h0, const _Float16* __restrict__ W1p,
    const float* __restrict__ b1, const _Float16* __restrict__ W2p,
    const float* __restrict__ b2, float* __restrict__ outf,
    _Float16* __restrict__ outh) {
    __shared__ _Float16 sG[64 * 136];
    int n0 = blockIdx.x * 64;
    int t = threadIdx.x;
    int w = t >> 6, lane = t & 63, q = lane >> 4, r16 = lane & 15;
    int mrow = w * 16 + r16;
    int grow = n0 + mrow;
    int growc = grow < N_NODES ? grow : N_NODES - 1;
    const _Float16* hrow = h0 + (size_t)growc * D;

    half8_t av[4];
#pragma unroll
    for (int kb = 0; kb < 4; kb++)
        av[kb] = *(const half8_t*)(hrow + kb * 32 + q * 8);

    floatx4 acc[8];
#pragma unroll
    for (int nb = 0; nb < 8; nb++) acc[nb] = floatx4{0.f, 0.f, 0.f, 0.f};
#pragma unroll
    for (int kb = 0; kb < 4; kb++) {
#pragma unroll
        for (int nb = 0; nb < 8; nb++) {
            half8_t bv = *(const half8_t*)(W1p + (size_t)((kb * 8 + nb) * 64 + lane) * 8);
            acc[nb] = __builtin_amdgcn_mfma_f32_16x16x32_f16(av[kb], bv, acc[nb], 0, 0, 0);
        }
    }
#pragma unroll
    for (int nb = 0; nb < 8; nb++) {
        int col = nb * 16 + r16;
        float bb = b1[col];
#pragma unroll
        for (int r = 0; r < 4; r++) {
            float v = acc[nb][r] + bb;
            float gl = 0.5f * v * (1.0f + erff(v * 0.70710678118654752f));
            sG[(w * 16 + q * 4 + r) * 136 + col] = (_Float16)gl;
        }
    }
    // wave w wrote exactly the sG rows it reads below — no barrier needed

#pragma unroll
    for (int kb = 0; kb < 4; kb++)
        av[kb] = *(const half8_t*)&sG[mrow * 136 + kb * 32 + q * 8];
#pragma unroll
    for (int nb = 0; nb < 8; nb++) acc[nb] = floatx4{0.f, 0.f, 0.f, 0.f};
#pragma unroll
    for (int kb = 0; kb < 4; kb++) {
#pragma unroll
        for (int nb = 0; nb < 8; nb++) {
            half8_t bv = *(const half8_t*)(W2p + (size_t)((kb * 8 + nb) * 64 + lane) * 8);
            acc[nb] = __builtin_amdgcn_mfma_f32_16x16x32_f16(av[kb], bv, acc[nb], 0, 0, 0);
        }
    }
#pragma unroll
    for (int nb = 0; nb < 8; nb++) {
        int col = nb * 16 + r16;
        float bb = b2[col];
#pragma unroll
        for (int r = 0; r < 4; r++) {
            int n = n0 + w * 16 + q * 4 + r;
            if (n < N_NODES) {
                float v = acc[nb][r] + bb;
                if (LAST) {
                    __builtin_nontemporal_store(v, &outf[(size_t)n * D + col]);
                } else {
                    outh[(size_t)n * D + col] = (_Float16)v;
                }
            }
        }
    }
}

// ---------------- launch ----------------

static inline size_t align_up(size_t v, size_t a) { return (v + a - 1) & ~(a - 1); }

extern "C" void kernel_launch(void* const* d_in, const int* in_sizes, int n_in,
                              void* d_out, int out_size, void* d_ws, size_t ws_size,
                              hipStream_t stream) {
    const float* x         = (const float*)d_in[0];
    const float* edge_attr = (const float*)d_in[1];
    const float* W1        = (const float*)d_in[2];
    const float* b1        = (const float*)d_in[3];
    const float* W2        = (const float*)d_in[4];
    const float* b2        = (const float*)d_in[5];
    const float* We        = (const float*)d_in[6];
    const float* be        = (const float*)d_in[7];
    const float* eps       = (const float*)d_in[8];
    const int*   src       = (const int*)d_in[9];
    const int*   dst       = ((const int*)d_in[9]) + N_EDGES;

    char* w = (char*)d_ws;
    int*  off    = (int*)w;  w += align_up((N_NODES + 1) * sizeof(int), 16);
    int*  deg    = (int*)w;  w += N_NODES * sizeof(int);        // deg + bflag contiguous
    int*  bflag  = (int*)w;  w += 64 * sizeof(int);             // (memset'd together)
    int*  head   = (int*)w;  w += align_up(N_NODES * sizeof(int), 16);
    int*  bsum   = (int*)w;  w += 64 * sizeof(int);
    int*  sorted = (int*)w;  w += align_up((size_t)N_EDGES * sizeof(int), 16);
    _Float16* xb0 = (_Float16*)w; w += (size_t)N_NODES * D * 2;
    _Float16* xb1 = (_Float16*)w; w += (size_t)N_NODES * D * 2;
    _Float16* h0b = (_Float16*)w; w += (size_t)N_NODES * D * 2;
    _Float16* ea_s = (_Float16*)w; w += (size_t)N_EDGES * E_DIM * 2 + 1024;
    _Float16* Wp  = (_Float16*)w; w += (size_t)6 * 16384 * 2;
    _Float16* Weh = (_Float16*)w; w += (size_t)3 * 2048 * 2;

    // ---- CSR build + prep: 4 dispatches ----
    hipMemsetAsync(deg, 0, (N_NODES + 64) * sizeof(int), stream);   // deg + bflag
    k_prep<<<NB_PRE + NB_H, 256, 0, stream>>>(
        x, W1, W2, We, dst, xb0, Wp, Weh, deg);
    k_scan<<<SCAN_BLOCKS, 256, 0, stream>>>(deg, off, head, bsum, bflag);
    k_scatter<<<(N_EDGES + 255) / 256, 256, 0, stream>>>(
        src, dst, head, sorted, edge_attr, ea_s);

    // ---- 3 layers ----
    _Float16* xcur = xb0;
    _Float16* xnxt = xb1;
    for (int l = 0; l < DEPTH; l++) {
        k_agg<<<AGG_BLOCKS, 256, 0, stream>>>(
            xcur, ea_s, sorted, off,
            Weh + (size_t)l * 2048, be + (size_t)l * D, eps + l, h0b);
        const _Float16* W1p = Wp + (size_t)(l * 2 + 0) * 16384;
        const _Float16* W2p = Wp + (size_t)(l * 2 + 1) * 16384;
        if (l == DEPTH - 1) {
            k_mlp<true><<<(N_NODES + 63) / 64, 256, 0, stream>>>(
                h0b, W1p, b1 + (size_t)l * D, W2p, b2 + (size_t)l * D,
                (float*)d_out, nullptr);
        } else {
            k_mlp<false><<<(N_NODES + 63) / 64, 256, 0, stream>>>(
                h0b, W1p, b1 + (size_t)l * D, W2p, b2 + (size_t)l * D,
                nullptr, xnxt);
        }
        _Float16* tmp = xcur; xcur = xnxt; xnxt = tmp;
    }
}